// Round 4
// baseline (4556.039 us; speedup 1.0000x reference)
//
#include <hip/hip_runtime.h>
#include <hip/hip_fp16.h>

typedef _Float16 f16;
typedef __attribute__((ext_vector_type(8))) _Float16 f16x8;
typedef __attribute__((ext_vector_type(16))) float f32x16;

#define GLL(src, dst) __builtin_amdgcn_global_load_lds( \
    (const __attribute__((address_space(1))) void*)(src), \
    (__attribute__((address_space(3))) void*)(dst), 16, 0, 0)

// ---------------------------------------------------------------------------
// Core tile GEMM: C[128 x 128] = A[128 x K] * B(rows)[128 x K]^T
// v_mfma_f32_32x32x16_f16, 512 threads = 8 waves as 2 (row-halves of 64) x
// 4 (col-quarters of 32). Each wave: 2x1 32x32 tiles -> acc f32x16[2].
// B tile row r -> global row nbase + (r>>5)*nstride + (r&31).
//
// BK=64, double-buffered LDS (2 x 32KB), counted-vmcnt prefetch: per iter
// vmcnt(4) waits current tile only; next tile's 4 loads stay in flight.
// 2 waves/SIMD provide the latency hiding (R3's 4-wave/1-per-SIMD version
// was latency-bound at 53.9us; R1's 2-blocks/CU 16x16 version was
// LDS-BW-bound at 28.5us -- this keeps 32x32's halved LDS traffic AND
// restores 2 waves/SIMD).
//
// LDS layout: [row][8 chunks of 8 f16], chunk XOR (row&7); global source
// pre-swizzled so global_load_lds dest stays linear (HW: base + lane*16).
// Frag read: 8 consecutive lanes hit 8 distinct chunk slots -> 32 banks.
//
// Operand layouts (HW-verified in R3, passed absmax 9.8e-4):
//   A/B frag: row = lane&31, k = (lane>>5)*8 + e (f16x8 contiguous).
//   C/D:      col = lane&31, row = (reg&3) + 8*(reg>>2) + 4*(lane>>5).
// ---------------------------------------------------------------------------
__device__ __forceinline__ void gemm_core(
    const f16* __restrict__ A, int lda,
    const f16* __restrict__ Bm, int ldb,
    int K, int bm0, int nbase, int nstride,
    unsigned char* __restrict__ smem, f32x16 acc[2])
{
    const int tid  = threadIdx.x;          // 0..511
    const int wave = tid >> 6;             // 0..7
    const int wr   = wave >> 2;            // 0..1 : 64-row half
    const int wc   = wave & 3;             // 0..3 : 32-col quarter
    const int lane = tid & 63;
    const int l31  = lane & 31;
    const int hi   = lane >> 5;

    #pragma unroll
    for (int mt = 0; mt < 2; ++mt)
      #pragma unroll
      for (int e = 0; e < 16; ++e)
        acc[mt][e] = 0.f;

    // staging: A tile 128x64 f16 = 1024 chunks -> 2 passes of 512; B same
    const f16* gA[2]; const f16* gB[2];
    int ldA[2], ldB[2];
    #pragma unroll
    for (int p = 0; p < 2; ++p) {
        int s  = p * 512 + tid;
        int r  = s >> 3;
        int cg = (s & 7) ^ (r & 7);            // pre-swizzled global chunk
        gA[p] = A + (size_t)(bm0 + r) * lda + cg * 8;
        int brow = nbase + (r >> 5) * nstride + (r & 31);
        gB[p] = Bm + (size_t)brow * ldb + cg * 8;
        ldA[p] = (p * 512 + wave * 64) * 16;   // linear dest, bytes
        ldB[p] = 16384 + (p * 512 + wave * 64) * 16;
    }

    // fragment offsets (f16 elements); chunk c = kk*2 + hi, slot = c^(row&7)
    int offA[2][4], offB[4];
    #pragma unroll
    for (int mt = 0; mt < 2; ++mt) {
        int ra = wr * 64 + mt * 32 + l31;
        #pragma unroll
        for (int kk = 0; kk < 4; ++kk)
            offA[mt][kk] = (ra * 8 + ((kk * 2 + hi) ^ (ra & 7))) * 8;
    }
    {
        int rb = wc * 32 + l31;
        #pragma unroll
        for (int kk = 0; kk < 4; ++kk)
            offB[kk] = 8192 + (rb * 8 + ((kk * 2 + hi) ^ (rb & 7))) * 8;
    }

    auto stage = [&](int buf, int t2) {        // 4 loads per thread
        unsigned char* base = smem + buf * 32768;
        const int k0 = t2 * 64;
        #pragma unroll
        for (int p = 0; p < 2; ++p) GLL(gA[p] + k0, base + ldA[p]);
        #pragma unroll
        for (int p = 0; p < 2; ++p) GLL(gB[p] + k0, base + ldB[p]);
    };

    const int niter = K >> 6;                  // callers: K in {128, 2048}
    stage(0, 0);
    stage(1, 1);
    for (int t = 0; t < niter; ++t) {
        if (t + 1 < niter)
            asm volatile("s_waitcnt vmcnt(4)" ::: "memory");  // tile t landed
        else
            asm volatile("s_waitcnt vmcnt(0)" ::: "memory");
        __builtin_amdgcn_s_barrier();
        const f16* base = (const f16*)(smem + (t & 1) * 32768);
        f16x8 af[2][4], bf[4];
        #pragma unroll
        for (int mt = 0; mt < 2; ++mt)
          #pragma unroll
          for (int kk = 0; kk < 4; ++kk)
            af[mt][kk] = *(const f16x8*)(base + offA[mt][kk]);
        #pragma unroll
        for (int kk = 0; kk < 4; ++kk)
            bf[kk] = *(const f16x8*)(base + offB[kk]);
        asm volatile("s_waitcnt lgkmcnt(0)" ::: "memory");
        __builtin_amdgcn_sched_barrier(0);     // rule #18: fence MFMA hoist
        __builtin_amdgcn_s_barrier();          // buf (t&1) read-released
        if (t + 2 < niter) stage(t & 1, t + 2);
        #pragma unroll
        for (int kk = 0; kk < 4; ++kk)
          #pragma unroll
          for (int mt = 0; mt < 2; ++mt)
            acc[mt] = __builtin_amdgcn_mfma_f32_32x32x16_f16(
                af[mt][kk], bf[kk], acc[mt], 0, 0, 0);
    }
}

// ---------------------------------------------------------------------------
// One recurrent step (also step 0 with A=x0,K=128,W=W_ih):
//   gates = A @ W^T + bias ; cell ; write h (fp16) and c (fp32)
// Block: [128 batch x 32 hidden x 4 gates] (128 cols). Gates land in
// different waves -> exchange via LDS G[128][128] f32 (reuses staging smem),
// then each thread computes 8 cells.
// ---------------------------------------------------------------------------
__global__ __launch_bounds__(512, 2) void k_step(
    const f16* __restrict__ A, int lda, int K,
    const f16* __restrict__ W, int ldb,
    const float* __restrict__ bias,
    float* __restrict__ Cst,
    f16* __restrict__ Hout)
{
    __shared__ alignas(16) unsigned char smem[65536];
    const int hid0 = blockIdx.x * 32;
    const int bm0  = blockIdx.y * 128;
    f32x16 acc[2];
    gemm_core(A, lda, W, ldb, K, bm0, hid0, 2048, smem, acc);

    const int tid = threadIdx.x;
    const int wave = tid >> 6, wr = wave >> 2, wc = wave & 3;
    const int lane = tid & 63, l31 = lane & 31, hi = lane >> 5;
    float* G = (float*)smem;   // [128 rows][128 cols]; col = gate*32 + hid_l
    #pragma unroll
    for (int mt = 0; mt < 2; ++mt) {
        const int col = wc * 32 + l31;
        #pragma unroll
        for (int reg = 0; reg < 16; ++reg) {
            const int row = wr * 64 + mt * 32 + (reg & 3) + 8 * (reg >> 2) + 4 * hi;
            G[row * 128 + col] = acc[mt][reg];
        }
    }
    __syncthreads();
    const int hl  = tid & 31;
    const int r16 = tid >> 5;          // 0..15
    const int hid = hid0 + hl;
    const float bI = bias[hid];
    const float bF = bias[2048 + hid];
    const float bG = bias[4096 + hid];
    const float bO = bias[6144 + hid];
    #pragma unroll
    for (int j = 0; j < 8; ++j) {
        const int row = j * 16 + r16;
        const float* g = G + row * 128;
        float iv = g[hl]      + bI;
        float fv = g[32 + hl] + bF;
        float gv = g[64 + hl] + bG;
        float ov = g[96 + hl] + bO;
        float si = 1.f / (1.f + __expf(-iv));
        float sf = 1.f / (1.f + __expf(-fv));
        float so = 1.f / (1.f + __expf(-ov));
        float tg = tanhf(gv);
        const size_t idx = (size_t)(bm0 + row) * 2048 + hid;
        float c = sf * Cst[idx] + si * tg;
        Cst[idx] = c;
        Hout[idx] = (f16)(so * tanhf(c));
    }
}

// out[b, t, d] = H[slot, b, :] @ W_out[d, :] + b_out[d];  t = t0 + slot
// One block covers all 128 output dims x 128 M-rows.
__global__ __launch_bounds__(512, 2) void k_out(
    const f16* __restrict__ Hbase,
    const f16* __restrict__ Wout,
    const float* __restrict__ bout,
    float* __restrict__ out, int t0)
{
    __shared__ alignas(16) unsigned char smem[65536];
    const int bm0 = blockIdx.y * 128;  // over M = depth*512
    f32x16 acc[2];
    gemm_core(Hbase, 2048, Wout, 2048, 2048, bm0, 0, 32, smem, acc);
    const int tid = threadIdx.x;
    const int wave = tid >> 6, wr = wave >> 2, wc = wave & 3;
    const int lane = tid & 63, l31 = lane & 31, hi = lane >> 5;
    const int d = wc * 32 + l31;
    const float bo = bout[d];
    #pragma unroll
    for (int mt = 0; mt < 2; ++mt) {
        #pragma unroll
        for (int reg = 0; reg < 16; ++reg) {
            const int row = wr * 64 + mt * 32 + (reg & 3) + 8 * (reg >> 2) + 4 * hi;
            const int m = bm0 + row;
            const int slot = m >> 9, b = m & 511;
            out[(size_t)b * 16384 + (t0 + slot) * 128 + d] = acc[mt][reg] + bo;
        }
    }
}

// ---------------- prep kernels (run once per launch) ------------------------

__global__ void k_cast(const float* __restrict__ s, f16* __restrict__ d, int n)
{
    int i = blockIdx.x * 256 + threadIdx.x;
    if (i < n) d[i] = (f16)s[i];
}

__global__ void k_x0(const float* __restrict__ tgt, f16* __restrict__ x0)
{
    int i = blockIdx.x * 256 + threadIdx.x;  // 65536 total
    int b = i >> 7, d = i & 127;
    x0[i] = (f16)tgt[(size_t)b * 16384 + d];  // tgt[b, 0, d]
}

__global__ void k_bias(const float* __restrict__ bih, const float* __restrict__ bhh,
                       const float* __restrict__ Wih, const float* __restrict__ bout,
                       float* __restrict__ b0, float* __restrict__ bp)
{
    int r = blockIdx.x * 256 + threadIdx.x;
    if (r >= 8192) return;
    float s = bih[r] + bhh[r];
    float a = 0.f;
    for (int d = 0; d < 128; ++d) a += Wih[(size_t)r * 128 + d] * bout[d];
    b0[r] = s;        // step-0 bias
    bp[r] = s + a;    // recurrent bias (absorbs W_ih @ b_out)
}

// WoutT[k][d] = (f16) Wout[d][k]   (2048 x 128, MFMA B-operand for k_wcomb2)
__global__ void k_wt(const float* __restrict__ Wout, f16* __restrict__ WoutT)
{
    __shared__ float tile[64][65];
    const int k0 = blockIdx.x * 64;   // 32
    const int d0 = blockIdx.y * 64;   // 2
    const int tid = threadIdx.x;
    const int c = tid & 63, rr = tid >> 6;
    #pragma unroll
    for (int i = 0; i < 16; ++i) {
        int d = rr + i * 4;
        tile[d][c] = Wout[(size_t)(d0 + d) * 2048 + k0 + c];
    }
    __syncthreads();
    #pragma unroll
    for (int i = 0; i < 16; ++i) {
        int k = rr + i * 4;
        WoutT[(size_t)(k0 + k) * 128 + d0 + c] = (f16)tile[c][k];
    }
}

// Wc[r,k] = Whh[r,k] + W_ih[r,:] @ W_out[:,k]  via MFMA
__global__ __launch_bounds__(512, 2) void k_wcomb2(
    const f16* __restrict__ Wih16, const f16* __restrict__ WoutT,
    const float* __restrict__ Whh, f16* __restrict__ Wc)
{
    __shared__ alignas(16) unsigned char smem[65536];
    const int n0  = blockIdx.x * 128;  // 16 col-blocks over k
    const int bm0 = blockIdx.y * 128;  // 64 row-blocks over r
    f32x16 acc[2];
    gemm_core(Wih16, 128, WoutT, 128, 128, bm0, n0, 32, smem, acc);
    const int tid = threadIdx.x;
    const int wave = tid >> 6, wr = wave >> 2, wc = wave & 3;
    const int lane = tid & 63, l31 = lane & 31, hi = lane >> 5;
    const int k = n0 + wc * 32 + l31;
    #pragma unroll
    for (int mt = 0; mt < 2; ++mt) {
        #pragma unroll
        for (int reg = 0; reg < 16; ++reg) {
            const int row = wr * 64 + mt * 32 + (reg & 3) + 8 * (reg >> 2) + 4 * hi;
            const size_t r = (size_t)(bm0 + row);
            Wc[r * 2048 + k] = (f16)(acc[mt][reg] + Whh[r * 2048 + k]);
        }
    }
}

// ---------------------------------------------------------------------------

extern "C" void kernel_launch(void* const* d_in, const int* in_sizes, int n_in,
                              void* d_out, int out_size, void* d_ws, size_t ws_size,
                              hipStream_t stream)
{
    const float* tgt  = (const float*)d_in[0];
    const float* Wih  = (const float*)d_in[1];
    const float* Whh  = (const float*)d_in[2];
    const float* bih  = (const float*)d_in[3];
    const float* bhh  = (const float*)d_in[4];
    const float* Wout = (const float*)d_in[5];
    const float* bout = (const float*)d_in[6];
    float* out = (float*)d_out;

    char* ws = (char*)d_ws;
    size_t off = 0;
    auto alloc = [&](size_t bytes) -> void* {
        void* p = ws + off;
        off += (bytes + 255) & ~(size_t)255;
        return p;
    };
    f16*   Wc     = (f16*)alloc((size_t)8192 * 2048 * 2);  // combined W_hh + W_ih*W_out
    f16*   Wih16  = (f16*)alloc((size_t)8192 * 128 * 2);
    f16*   Wout16 = (f16*)alloc((size_t)128 * 2048 * 2);
    f16*   WoutT  = (f16*)alloc((size_t)2048 * 128 * 2);
    f16*   x0     = (f16*)alloc((size_t)512 * 128 * 2);
    float* b0     = (float*)alloc(8192 * 4);
    float* bp     = (float*)alloc(8192 * 4);
    float* Cst    = (float*)alloc((size_t)512 * 2048 * 4);

    const size_t slotsz = (size_t)512 * 2048;  // elements per h snapshot
    int depth = 0;
    const int cands[7] = {128, 64, 32, 16, 8, 4, 2};
    for (int i = 0; i < 7; ++i)
        if (off + (size_t)cands[i] * slotsz * 2 <= ws_size) { depth = cands[i]; break; }
    if (depth == 0) return;  // workspace too small for any configuration
    f16* Hbuf = (f16*)alloc((size_t)depth * slotsz * 2);

    hipMemsetAsync(Cst, 0, (size_t)512 * 2048 * 4, stream);
    k_cast<<<dim3(4096), dim3(256), 0, stream>>>(Wih, Wih16, 1048576);
    k_cast<<<dim3(1024), dim3(256), 0, stream>>>(Wout, Wout16, 262144);
    k_wt<<<dim3(32, 2), dim3(256), 0, stream>>>(Wout, WoutT);
    k_x0<<<dim3(256), dim3(256), 0, stream>>>(tgt, x0);
    k_bias<<<dim3(32), dim3(256), 0, stream>>>(bih, bhh, Wih, bout, b0, bp);
    k_wcomb2<<<dim3(16, 64), dim3(512), 0, stream>>>(Wih16, WoutT, Whh, Wc);

    // step 0: gates = x0 @ W_ih^T + (b_ih+b_hh)  -> h^1 in slot 0
    k_step<<<dim3(64, 4), dim3(512), 0, stream>>>(x0, 128, 128, Wih16, 128, b0, Cst, Hbuf);
    // steps 1..127: gates = h @ W'^T + b'
    for (int s = 1; s < 128; ++s) {
        if ((s % depth) == 0)  // slots 0..depth-1 hold h^(s-depth+1..s) -> out t in [s-depth, s)
            k_out<<<dim3(1, depth * 4), dim3(512), 0, stream>>>(Hbuf, Wout16, bout, out, s - depth);
        k_step<<<dim3(64, 4), dim3(512), 0, stream>>>(
            Hbuf + (size_t)((s - 1) % depth) * slotsz, 2048, 2048, Wc, 2048, bp,
            Cst, Hbuf + (size_t)(s % depth) * slotsz);
    }
    k_out<<<dim3(1, depth * 4), dim3(512), 0, stream>>>(Hbuf, Wout16, bout, out, 128 - depth);
}